// Round 10
// baseline (113.123 us; speedup 1.0000x reference)
//
#include <hip/hip_runtime.h>
#include <math.h>

// ---------------------------------------------------------------------------
// OBB CIoU loss, N independent box pairs -> scalar mean.
// R10: single-variable experiment on R9 (44.4 us, VALUBusy 69%, idle ~30%
// invariant to occupancy): DO NOT unroll the PAIRS loop. R9/R6 inlined the
// ~1700-inst body 2x/4x (~27/54 KB straight-line code) -- at/over the 32 KB
// L1I; all waves fetch-stall identically, which more waves cannot hide
// (explains R9's null occupancy result). One body (~14 KB) fits L1I.
// R5/R9 showed the compiler never interleaved the pair chains (VGPR ~52-56
// throughout), so no ILP is lost by rolling the loop.
// Carried: bf16 payload slab (R8, absmax-0.0-validated), packed-uint key
// Batcher sort + LDS gather (R6), 16-vertex compacted candidates (R4),
// v_rcp divides + diamond pseudo-angle (R3/R6), native sin/cos (R5),
// PAIRS=2 (R8/R9), exact-reference algorithm semantics.
// ---------------------------------------------------------------------------

#define BLOCK 256
#define NV 16
#define PAIRS 2
#define LDS_STRIDE 17   // 16 dword slots + 1 pad (odd stride -> free aliasing)

// --- compile-time Batcher odd-even mergesort network for n=16 ---
struct CEList {
    int n;
    unsigned char lo[128];
    unsigned char hi[128];
};

constexpr CEList make_ces16() {
    CEList L{};
    L.n = 0;
    for (int p = 1; p < NV; p <<= 1)
        for (int k = p; k >= 1; k >>= 1)
            for (int j = k % p; j + k < NV; j += 2 * k)
                for (int i = 0; i < k; i++) {
                    int lo = i + j, hi = i + j + k;
                    if (hi < NV && (lo / (2 * p)) == (hi / (2 * p))) {
                        L.lo[L.n] = (unsigned char)lo;
                        L.hi[L.n] = (unsigned char)hi;
                        L.n++;
                    }
                }
    return L;
}

constexpr CEList CES = make_ces16();

__device__ __forceinline__ float frcp(float x) {
    return __builtin_amdgcn_rcpf(x);
}

// Diamond pseudo-angle, no wrap: range [0,4), a cyclic shift of atan2 order.
// Cyclic shoelace is shift-invariant. All values nonneg -> uint-monotone.
__device__ __forceinline__ float angle_key(float x, float y) {
    float ax = fabsf(x), ay = fabsf(y);
    float den = ax + ay;
    float r = x * frcp(den);
    r = (den > 0.f) ? r : 0.f;
    return (y >= 0.f) ? (1.f - r) : (3.f + r);
}

// Pack two floats to bf16x2 with round-to-nearest (payload only; keys exact).
__device__ __forceinline__ unsigned int pack_bf2(float x, float y) {
    unsigned int bx = __float_as_uint(x) + 0x8000u;
    unsigned int by = __float_as_uint(y) + 0x8000u;
    return (by & 0xFFFF0000u) | (bx >> 16);
}

__device__ __forceinline__ float pair_loss(const float* __restrict__ p,
                                           const float* __restrict__ t,
                                           float wv,
                                           unsigned int* __restrict__ myb)
{
    const float EPSf  = 1e-8f;   // segment-intersection eps (reference EPS)
    const float TOLf  = 1e-6f;   // box_in_box tol
    const float MEPS  = 1e-6f;   // MODE_EPS
    const float PIf   = 3.14159265358979323846f;

    float pcx = p[0], pcy = p[1], pw = p[2], ph = p[3], pa = p[4];
    float tcx = t[0], tcy = t[1], tw = t[2], th = t[3], ta = t[4];

    // ---- corners ---- (|angles| <= pi/2+0.3: native sin/cos sufficient)
    float c1x[4], c1y[4], c2x[4], c2y[4];
    float ca = __cosf(pa), sa = __sinf(pa);
    float cb = __cosf(ta), sb = __sinf(ta);
    {
        const float xs[4] = { 0.5f, -0.5f, -0.5f, 0.5f };
        const float ys[4] = { -0.5f, -0.5f, 0.5f, 0.5f };
        #pragma unroll
        for (int k = 0; k < 4; k++) {
            float x4 = xs[k] * pw, y4 = ys[k] * ph;
            c1x[k] = x4 * ca - y4 * sa + pcx;
            c1y[k] = x4 * sa + y4 * ca + pcy;
            float x4b = xs[k] * tw, y4b = ys[k] * th;
            c2x[k] = x4b * cb - y4b * sb + tcx;
            c2y[k] = x4b * sb + y4b * cb + tcy;
        }
    }

    // ---- 16 candidate vertices + validity masks ----
    float vx[NV], vy[NV];
    bool  msk[NV];

    // corners1 inside box2  (verts 0..3)
    {
        float ax = c2x[0], ay = c2y[0];
        float abx = c2x[1] - ax, aby = c2y[1] - ay;
        float adx = c2x[3] - ax, ady = c2y[3] - ay;
        float rab = frcp(abx * abx + aby * aby);
        float rad = frcp(adx * adx + ady * ady);
        #pragma unroll
        for (int k = 0; k < 4; k++) {
            float amx = c1x[k] - ax, amy = c1y[k] - ay;
            float pab = (abx * amx + aby * amy) * rab;
            float pad = (adx * amx + ady * amy) * rad;
            msk[k] = (pab > -TOLf) && (pab < 1.f + TOLf) &&
                     (pad > -TOLf) && (pad < 1.f + TOLf);
            vx[k] = c1x[k]; vy[k] = c1y[k];
        }
    }
    // corners2 inside box1  (verts 4..7)
    {
        float ax = c1x[0], ay = c1y[0];
        float abx = c1x[1] - ax, aby = c1y[1] - ay;
        float adx = c1x[3] - ax, ady = c1y[3] - ay;
        float rab = frcp(abx * abx + aby * aby);
        float rad = frcp(adx * adx + ady * ady);
        #pragma unroll
        for (int k = 0; k < 4; k++) {
            float amx = c2x[k] - ax, amy = c2y[k] - ay;
            float pab = (abx * amx + aby * amy) * rab;
            float pad = (adx * amx + ady * amy) * rad;
            msk[4 + k] = (pab > -TOLf) && (pab < 1.f + TOLf) &&
                         (pad > -TOLf) && (pad < 1.f + TOLf);
            vx[4 + k] = c2x[k]; vy[4 + k] = c2y[k];
        }
    }
    // edge x edge intersections, compacted 4 -> 2 per box1 edge
    #pragma unroll
    for (int e1 = 0; e1 < 4; e1++) {
        float x1 = c1x[e1], y1 = c1y[e1];
        float x2 = c1x[(e1 + 1) & 3], y2 = c1y[(e1 + 1) & 3];
        float ex = x2 - x1, ey = y2 - y1;
        float qx[4], qy[4];
        bool  qm[4];
        #pragma unroll
        for (int e2 = 0; e2 < 4; e2++) {
            float x3 = c2x[e2], y3 = c2y[e2];
            float x4 = c2x[(e2 + 1) & 3], y4 = c2y[(e2 + 1) & 3];
            float fx = x4 - x3, fy = y4 - y3;
            float num   = fy * ex - fx * ey;
            float rnum  = frcp(num + EPSf);
            float den_t = fx * (y1 - y3) - fy * (x1 - x3);
            float tt = den_t * rnum;
            float den_u = ex * (y1 - y3) - ey * (x1 - x3);
            float uu = -den_u * rnum;
            qm[e2] = (num != 0.f) && (tt > 0.f) && (tt < 1.f)
                                  && (uu > 0.f) && (uu < 1.f);
            qx[e2] = x1 + tt * ex;
            qy[e2] = y1 + tt * ey;
        }
        bool  mfL = qm[0] || qm[1];
        float fLx = qm[0] ? qx[0] : qx[1];
        float fLy = qm[0] ? qy[0] : qy[1];
        bool  msL = qm[0] && qm[1];
        bool  mfR = qm[2] || qm[3];
        float fRx = qm[2] ? qx[2] : qx[3];
        float fRy = qm[2] ? qy[2] : qy[3];
        bool  msR = qm[2] && qm[3];
        int s0 = 8 + 2 * e1, s1 = s0 + 1;
        vx[s0]  = mfL ? fLx : fRx;
        vy[s0]  = mfL ? fLy : fRy;
        msk[s0] = mfL || mfR;
        float tx = msL ? qx[1] : fRx;
        float ty = msL ? qy[1] : fRy;
        vx[s1]  = mfL ? tx : qx[3];
        vy[s1]  = mfL ? ty : qy[3];
        msk[s1] = msL || (mfL && mfR) || msR;
    }

    // ---- centroid of valid verts ----
    float sx = 0.f, sy = 0.f, cnt = 0.f;
    #pragma unroll
    for (int k = 0; k < NV; k++) {
        sx  += msk[k] ? vx[k] : 0.f;
        sy  += msk[k] ? vy[k] : 0.f;
        cnt += msk[k] ? 1.f : 0.f;
    }
    float rden = frcp(fmaxf(cnt, 1.f));
    float cxc = sx * rden, cyc = sy * rden;

    // ---- relative coords -> LDS scatter (bf16x2) + packed key (key|slot) ----
    unsigned int ku[NV];
    #pragma unroll
    for (int k = 0; k < NV; k++) {
        float rx = vx[k] - cxc, ry = vy[k] - cyc;
        myb[k] = pack_bf2(rx, ry);
        float a = msk[k] ? angle_key(rx, ry) : 1e7f;  // key from FULL floats
        ku[k] = (__float_as_uint(a) & 0xFFFFFFF0u) | (unsigned int)k;
    }

    // ---- sort 16 packed keys (Batcher network, 2 VALU per CE) ----
    #pragma unroll
    for (int c = 0; c < CES.n; c++) {
        const int lo = CES.lo[c], hi = CES.hi[c];
        unsigned int a = ku[lo], b = ku[hi];
        ku[lo] = a < b ? a : b;
        ku[hi] = a < b ? b : a;
    }

    // ---- gather payload by sorted index; shoelace ----
    const unsigned int VALID_LIM = 0x49742400u;  // bits of 1e6f
    float gx[NV], gy[NV];
    bool  gv[NV];
    #pragma unroll
    for (int k = 0; k < NV; k++) {
        unsigned int pk = myb[ku[k] & 15u];
        gx[k] = __uint_as_float(pk << 16);
        gy[k] = __uint_as_float(pk & 0xFFFF0000u);
        gv[k] = ku[k] < VALID_LIM;
    }
    float fx = gx[0], fy = gy[0];
    float cross = 0.f;
    #pragma unroll
    for (int k = 0; k < NV; k++) {
        int kn = (k + 1) % NV;           // constant after unroll
        float axv = gv[k]  ? gx[k]  : fx, ayv = gv[k]  ? gy[k]  : fy;
        float bxv = gv[kn] ? gx[kn] : fx, byv = gv[kn] ? gy[kn] : fy;
        cross += axv * byv - ayv * bxv;
    }
    float inter = fabsf(cross) * 0.5f;

    // ---- CIoU ----
    float area1 = pw * ph, area2 = tw * th;
    float iou = inter / (area1 + area2 - inter);
    iou = fminf(fmaxf(iou, 0.f), 1.f);

    float cA = fabsf(ca), sA = fabsf(sa);
    float cB = fabsf(cb), sB = fabsf(sb);
    float dw1 = (pw * cA + ph * sA) * 0.5f, dh1 = (pw * sA + ph * cA) * 0.5f;
    float dw2 = (tw * cB + th * sB) * 0.5f, dh2 = (tw * sB + th * cB) * 0.5f;
    float hp0 = pcx - dw1, hp1 = pcy - dh1, hp2 = pcx + dw1, hp3 = pcy + dh1;
    float ht0 = tcx - dw2, ht1 = tcy - dh2, ht2 = tcx + dw2, ht3 = tcy + dh2;

    float enw = fmaxf(fmaxf(hp2, ht2) - fminf(hp0, ht0), 0.f);
    float enh = fmaxf(fmaxf(hp3, ht3) - fminf(hp1, ht1), 0.f);
    float c2v = enw * enw + enh * enh + MEPS;
    float rho2 = (tcx - pcx) * (tcx - pcx) + (tcy - pcy) * (tcy - pcy);

    float factor = 4.f / (PIf * PIf);
    float dv = atanf(tw / (th + MEPS)) - atanf(pw / (ph + MEPS));
    float v_ = factor * dv * dv;
    float alpha = (iou > 0.5f) ? v_ / (1.f - iou + v_ + MEPS) : 0.f;

    float rhoterm = fminf(fmaxf(rho2 / c2v, 0.f), 1.f);
    float ciou = iou - (rhoterm + alpha * v_);
    return (1.f - ciou) * wv;
}

__global__ __launch_bounds__(BLOCK)
void obb_ciou_kernel(const float* __restrict__ pred,
                     const float* __restrict__ tgt,
                     const float* __restrict__ wgt,
                     float* __restrict__ out,
                     int N, float invN)
{
    __shared__ unsigned int slab[BLOCK * LDS_STRIDE];
    unsigned int* myb = slab + (int)threadIdx.x * LDS_STRIDE;

    int blk0 = blockIdx.x * (BLOCK * PAIRS);
    float loss = 0.f;

    // ROLLED loop (one inlined body, ~14 KB of code -> fits 32 KB L1I).
    #pragma unroll 1
    for (int u = 0; u < PAIRS; u++) {
        int i = blk0 + u * BLOCK + (int)threadIdx.x;
        if (i < N)
            loss += pair_loss(pred + (size_t)i * 5, tgt + (size_t)i * 5,
                              wgt[i], myb);
    }

    // ---- reduction: wave shuffle -> LDS -> one atomic per block ----
    #pragma unroll
    for (int off = 32; off > 0; off >>= 1)
        loss += __shfl_down(loss, off, 64);

    __shared__ float red[BLOCK / 64];
    int wave = threadIdx.x >> 6;
    int lane = threadIdx.x & 63;
    if (lane == 0) red[wave] = loss;
    __syncthreads();
    if (threadIdx.x == 0) {
        float s = 0.f;
        #pragma unroll
        for (int w = 0; w < BLOCK / 64; w++) s += red[w];
        atomicAdd(out, s * invN);
    }
}

extern "C" void kernel_launch(void* const* d_in, const int* in_sizes, int n_in,
                              void* d_out, int out_size, void* d_ws, size_t ws_size,
                              hipStream_t stream) {
    const float* pred = (const float*)d_in[0];
    const float* tgt  = (const float*)d_in[1];
    const float* wgt  = (const float*)d_in[2];
    float* out = (float*)d_out;
    int N = in_sizes[2];  // weight element count == N boxes

    hipMemsetAsync(out, 0, sizeof(float) * (size_t)out_size, stream);

    int grid = (N + BLOCK * PAIRS - 1) / (BLOCK * PAIRS);
    obb_ciou_kernel<<<grid, BLOCK, 0, stream>>>(pred, tgt, wgt, out, N,
                                                1.f / (float)N);
}

// Round 11
// 108.527 us; speedup vs baseline: 1.0423x; 1.0423x over previous
//
#include <hip/hip_runtime.h>
#include <math.h>

// ---------------------------------------------------------------------------
// OBB CIoU loss, N independent box pairs -> scalar mean.
// R11: back to R9 structure (44.4 us best; R10 proved rolled loop is worse).
// Instruction cuts (~-250 VALU/pair of ~2400):
//  (a) float2 ext-vector arithmetic on all (x,y)-paired math -> v_pk_fma_f32/
//      v_pk_add_f32 (gfx90a+; op_sel makes scalar splats free)
//  (b) atan(r1)-atan(r2) = atan((r1-r2)/(1+r1*r2)) (exact for r1*r2>0), one
//      degree-11 minimax poly + 1/x flip, frcp divides -> replaces 2 ocml
//      atanf + 2 IEEE divides (~66 instr -> ~20). dv is squared so sign of
//      the identity result is irrelevant.
//  (c) frcp for iou / rho2/c2 / alpha divides.
// Carried: bf16 payload slab + packed-uint key Batcher sort + LDS gather
// (R6/R8), 16-vertex compacted candidates (R4), diamond pseudo-angle (R6),
// native sin/cos (R5), PAIRS=2 full-unroll (R9), exact-reference semantics.
// ---------------------------------------------------------------------------

#define BLOCK 256
#define NV 16
#define PAIRS 2
#define LDS_STRIDE 17   // 16 dword slots + 1 pad (odd stride -> free aliasing)

typedef float v2f __attribute__((ext_vector_type(2)));

// --- compile-time Batcher odd-even mergesort network for n=16 ---
struct CEList {
    int n;
    unsigned char lo[128];
    unsigned char hi[128];
};

constexpr CEList make_ces16() {
    CEList L{};
    L.n = 0;
    for (int p = 1; p < NV; p <<= 1)
        for (int k = p; k >= 1; k >>= 1)
            for (int j = k % p; j + k < NV; j += 2 * k)
                for (int i = 0; i < k; i++) {
                    int lo = i + j, hi = i + j + k;
                    if (hi < NV && (lo / (2 * p)) == (hi / (2 * p))) {
                        L.lo[L.n] = (unsigned char)lo;
                        L.hi[L.n] = (unsigned char)hi;
                        L.n++;
                    }
                }
    return L;
}

constexpr CEList CES = make_ces16();

__device__ __forceinline__ float frcp(float x) {
    return __builtin_amdgcn_rcpf(x);
}

__device__ __forceinline__ v2f splat2(float x) {
    v2f r; r.x = x; r.y = x; return r;
}

__device__ __forceinline__ float hadd2(v2f v) { return v.x + v.y; }

// Diamond pseudo-angle, no wrap: range [0,4), a cyclic shift of atan2 order.
// Cyclic shoelace is shift-invariant. All values nonneg -> uint-monotone.
__device__ __forceinline__ float angle_key(float x, float y) {
    float ax = fabsf(x), ay = fabsf(y);
    float den = ax + ay;
    float r = x * frcp(den);
    r = (den > 0.f) ? r : 0.f;
    return (y >= 0.f) ? (1.f - r) : (3.f + r);
}

// Pack two floats to bf16x2 with round-to-nearest (payload only; keys exact).
__device__ __forceinline__ unsigned int pack_bf2(float x, float y) {
    unsigned int bx = __float_as_uint(x) + 0x8000u;
    unsigned int by = __float_as_uint(y) + 0x8000u;
    return (by & 0xFFFF0000u) | (bx >> 16);
}

// atan(z) for z in [0,1]: degree-11 odd minimax, max err ~1.5e-5 rad.
__device__ __forceinline__ float atan01(float z) {
    float z2 = z * z;
    float p = -0.01172120f;
    p = p * z2 + 0.05265332f;
    p = p * z2 - 0.11643287f;
    p = p * z2 + 0.19354346f;
    p = p * z2 - 0.33262347f;
    p = p * z2 + 0.99997726f;
    return z * p;
}

__device__ __forceinline__ float pair_loss(const float* __restrict__ p,
                                           const float* __restrict__ t,
                                           float wv,
                                           unsigned int* __restrict__ myb)
{
    const float EPSf  = 1e-8f;   // segment-intersection eps (reference EPS)
    const float TOLf  = 1e-6f;   // box_in_box tol
    const float MEPS  = 1e-6f;   // MODE_EPS
    const float PIf   = 3.14159265358979323846f;

    float pcx = p[0], pcy = p[1], pw = p[2], ph = p[3], pa = p[4];
    float tcx = t[0], tcy = t[1], tw = t[2], th = t[3], ta = t[4];

    // ---- corners (packed) ---- (|angles| bounded: native sin/cos OK)
    float ca = __cosf(pa), sa = __sinf(pa);
    float cb = __cosf(ta), sb = __sinf(ta);
    v2f C1[4], C2[4];
    {
        const float xs[4] = { 0.5f, -0.5f, -0.5f, 0.5f };
        const float ys[4] = { -0.5f, -0.5f, 0.5f, 0.5f };
        v2f R1x = { ca, sa },  R1y = { -sa, cb };  // placeholder fixed below
        R1y.x = -sa; R1y.y = ca;
        v2f R2x = { cb, sb },  R2y = { -sb, cb };
        R2y.x = -sb; R2y.y = cb;
        v2f CT1 = { pcx, pcy }, CT2 = { tcx, tcy };
        #pragma unroll
        for (int k = 0; k < 4; k++) {
            float x4 = xs[k] * pw, y4 = ys[k] * ph;
            C1[k] = splat2(x4) * R1x + splat2(y4) * R1y + CT1;
            float x4b = xs[k] * tw, y4b = ys[k] * th;
            C2[k] = splat2(x4b) * R2x + splat2(y4b) * R2y + CT2;
        }
    }

    // ---- 16 candidate vertices + validity masks ----
    v2f  V[NV];
    bool msk[NV];

    // corners1 inside box2  (verts 0..3)
    {
        v2f A  = C2[0];
        v2f AB = C2[1] - A, AD = C2[3] - A;
        float rab = frcp(hadd2(AB * AB));
        float rad = frcp(hadd2(AD * AD));
        #pragma unroll
        for (int k = 0; k < 4; k++) {
            v2f AM = C1[k] - A;
            float pab = hadd2(AB * AM) * rab;
            float pad = hadd2(AD * AM) * rad;
            msk[k] = (pab > -TOLf) && (pab < 1.f + TOLf) &&
                     (pad > -TOLf) && (pad < 1.f + TOLf);
            V[k] = C1[k];
        }
    }
    // corners2 inside box1  (verts 4..7)
    {
        v2f A  = C1[0];
        v2f AB = C1[1] - A, AD = C1[3] - A;
        float rab = frcp(hadd2(AB * AB));
        float rad = frcp(hadd2(AD * AD));
        #pragma unroll
        for (int k = 0; k < 4; k++) {
            v2f AM = C2[k] - A;
            float pab = hadd2(AB * AM) * rab;
            float pad = hadd2(AD * AM) * rad;
            msk[4 + k] = (pab > -TOLf) && (pab < 1.f + TOLf) &&
                         (pad > -TOLf) && (pad < 1.f + TOLf);
            V[4 + k] = C2[k];
        }
    }
    // edge x edge intersections, compacted 4 -> 2 per box1 edge
    #pragma unroll
    for (int e1 = 0; e1 < 4; e1++) {
        v2f P1 = C1[e1];
        v2f E  = C1[(e1 + 1) & 3] - P1;
        v2f  Q[4];
        bool qm[4];
        #pragma unroll
        for (int e2 = 0; e2 < 4; e2++) {
            v2f P3 = C2[e2];
            v2f F  = C2[(e2 + 1) & 3] - P3;
            float num  = F.y * E.x - F.x * E.y;
            float rnum = frcp(num + EPSf);
            v2f D = P1 - P3;
            float den_t = F.x * D.y - F.y * D.x;
            float den_u = E.x * D.y - E.y * D.x;
            float tt = den_t * rnum;
            float uu = -den_u * rnum;
            qm[e2] = (num != 0.f) && (tt > 0.f) && (tt < 1.f)
                                  && (uu > 0.f) && (uu < 1.f);
            Q[e2] = splat2(tt) * E + P1;
        }
        bool mfL = qm[0] || qm[1];
        v2f  fL  = qm[0] ? Q[0] : Q[1];
        bool msL = qm[0] && qm[1];
        bool mfR = qm[2] || qm[3];
        v2f  fR  = qm[2] ? Q[2] : Q[3];
        bool msR = qm[2] && qm[3];
        int s0 = 8 + 2 * e1, s1 = s0 + 1;
        V[s0]   = mfL ? fL : fR;
        msk[s0] = mfL || mfR;
        v2f  t2 = msL ? Q[1] : fR;
        V[s1]   = mfL ? t2 : Q[3];
        msk[s1] = msL || (mfL && mfR) || msR;
    }

    // ---- centroid of valid verts ----
    v2f s2 = { 0.f, 0.f };
    float cnt = 0.f;
    const v2f Z2 = { 0.f, 0.f };
    #pragma unroll
    for (int k = 0; k < NV; k++) {
        s2  += msk[k] ? V[k] : Z2;
        cnt += msk[k] ? 1.f : 0.f;
    }
    float rden = frcp(fmaxf(cnt, 1.f));
    v2f cen = s2 * splat2(rden);

    // ---- relative coords -> LDS scatter (bf16x2) + packed key (key|slot) ----
    unsigned int ku[NV];
    #pragma unroll
    for (int k = 0; k < NV; k++) {
        v2f R = V[k] - cen;
        myb[k] = pack_bf2(R.x, R.y);
        float a = msk[k] ? angle_key(R.x, R.y) : 1e7f;  // key from FULL floats
        ku[k] = (__float_as_uint(a) & 0xFFFFFFF0u) | (unsigned int)k;
    }

    // ---- sort 16 packed keys (Batcher network, 2 VALU per CE) ----
    #pragma unroll
    for (int c = 0; c < CES.n; c++) {
        const int lo = CES.lo[c], hi = CES.hi[c];
        unsigned int a = ku[lo], b = ku[hi];
        ku[lo] = a < b ? a : b;
        ku[hi] = a < b ? b : a;
    }

    // ---- gather payload by sorted index; shoelace ----
    const unsigned int VALID_LIM = 0x49742400u;  // bits of 1e6f
    float gx[NV], gy[NV];
    bool  gv[NV];
    #pragma unroll
    for (int k = 0; k < NV; k++) {
        unsigned int pk = myb[ku[k] & 15u];
        gx[k] = __uint_as_float(pk << 16);
        gy[k] = __uint_as_float(pk & 0xFFFF0000u);
        gv[k] = ku[k] < VALID_LIM;
    }
    float fx = gx[0], fy = gy[0];
    float cross = 0.f;
    #pragma unroll
    for (int k = 0; k < NV; k++) {
        int kn = (k + 1) % NV;           // constant after unroll
        float axv = gv[k]  ? gx[k]  : fx, ayv = gv[k]  ? gy[k]  : fy;
        float bxv = gv[kn] ? gx[kn] : fx, byv = gv[kn] ? gy[kn] : fy;
        cross += axv * byv - ayv * bxv;
    }
    float inter = fabsf(cross) * 0.5f;

    // ---- CIoU ----
    float area1 = pw * ph, area2 = tw * th;
    float iou = inter * frcp(area1 + area2 - inter);
    iou = fminf(fmaxf(iou, 0.f), 1.f);

    float cA = fabsf(ca), sA = fabsf(sa);
    float cB = fabsf(cb), sB = fabsf(sb);
    float dw1 = (pw * cA + ph * sA) * 0.5f, dh1 = (pw * sA + ph * cA) * 0.5f;
    float dw2 = (tw * cB + th * sB) * 0.5f, dh2 = (tw * sB + th * cB) * 0.5f;
    float hp0 = pcx - dw1, hp1 = pcy - dh1, hp2 = pcx + dw1, hp3 = pcy + dh1;
    float ht0 = tcx - dw2, ht1 = tcy - dh2, ht2 = tcx + dw2, ht3 = tcy + dh2;

    float enw = fmaxf(fmaxf(hp2, ht2) - fminf(hp0, ht0), 0.f);
    float enh = fmaxf(fmaxf(hp3, ht3) - fminf(hp1, ht1), 0.f);
    float c2v = enw * enw + enh * enh + MEPS;
    float rho2 = (tcx - pcx) * (tcx - pcx) + (tcy - pcy) * (tcy - pcy);

    // v-term: atan(r1) - atan(r2) = atan((r1-r2)/(1+r1*r2)), exact for
    // r1*r2 > 0 (both aspect ratios positive). dv is squared -> sign-free.
    float factor = 4.f / (PIf * PIf);
    float r1 = tw * frcp(th + MEPS);
    float r2 = pw * frcp(ph + MEPS);
    float xd = (r1 - r2) * frcp(1.f + r1 * r2);
    float axd = fabsf(xd);
    bool  big = axd > 1.f;
    float z   = big ? frcp(axd) : axd;
    float at  = atan01(z);
    float dv  = big ? ((0.5f * PIf) - at) : at;   // |atan(xd)|
    float v_ = factor * dv * dv;
    float alpha = (iou > 0.5f) ? v_ * frcp(1.f - iou + v_ + MEPS) : 0.f;

    float rhoterm = fminf(fmaxf(rho2 * frcp(c2v), 0.f), 1.f);
    float ciou = iou - (rhoterm + alpha * v_);
    return (1.f - ciou) * wv;
}

__global__ __launch_bounds__(BLOCK)
void obb_ciou_kernel(const float* __restrict__ pred,
                     const float* __restrict__ tgt,
                     const float* __restrict__ wgt,
                     float* __restrict__ out,
                     int N, float invN)
{
    __shared__ unsigned int slab[BLOCK * LDS_STRIDE];
    unsigned int* myb = slab + (int)threadIdx.x * LDS_STRIDE;

    int blk0 = blockIdx.x * (BLOCK * PAIRS);
    float loss = 0.f;

    #pragma unroll
    for (int u = 0; u < PAIRS; u++) {
        int i = blk0 + u * BLOCK + (int)threadIdx.x;
        if (i < N)
            loss += pair_loss(pred + (size_t)i * 5, tgt + (size_t)i * 5,
                              wgt[i], myb);
    }

    // ---- reduction: wave shuffle -> LDS -> one atomic per block ----
    #pragma unroll
    for (int off = 32; off > 0; off >>= 1)
        loss += __shfl_down(loss, off, 64);

    __shared__ float red[BLOCK / 64];
    int wave = threadIdx.x >> 6;
    int lane = threadIdx.x & 63;
    if (lane == 0) red[wave] = loss;
    __syncthreads();
    if (threadIdx.x == 0) {
        float s = 0.f;
        #pragma unroll
        for (int w = 0; w < BLOCK / 64; w++) s += red[w];
        atomicAdd(out, s * invN);
    }
}

extern "C" void kernel_launch(void* const* d_in, const int* in_sizes, int n_in,
                              void* d_out, int out_size, void* d_ws, size_t ws_size,
                              hipStream_t stream) {
    const float* pred = (const float*)d_in[0];
    const float* tgt  = (const float*)d_in[1];
    const float* wgt  = (const float*)d_in[2];
    float* out = (float*)d_out;
    int N = in_sizes[2];  // weight element count == N boxes

    hipMemsetAsync(out, 0, sizeof(float) * (size_t)out_size, stream);

    int grid = (N + BLOCK * PAIRS - 1) / (BLOCK * PAIRS);
    obb_ciou_kernel<<<grid, BLOCK, 0, stream>>>(pred, tgt, wgt, out, N,
                                                1.f / (float)N);
}